// Round 1
// baseline (1881.830 us; speedup 1.0000x reference)
//
#include <hip/hip_runtime.h>
#include <cstdint>

#define N_NODES 50000
#define N_EDGES 800000
#define DIM_IN 128
#define HID 320
#define HEADS 4
#define HDIM 80
#define NEG_SLOPE 0.2f

// ======================= CSR build (counting sort by dst) =======================
__global__ void hist_kernel(const int* __restrict__ dst, int* __restrict__ hist, int E) {
  int e = blockIdx.x * 256 + threadIdx.x;
  if (e < E) atomicAdd(&hist[dst[e]], 1);
}

__global__ __launch_bounds__(1024) void scan_kernel(const int* __restrict__ hist,
                                                    int* __restrict__ row_off, int n) {
  __shared__ int part[1024];
  int t = threadIdx.x;
  int chunk = (n + 1023) >> 10;
  int beg = t * chunk;
  int end = beg + chunk;
  if (end > n) end = n;
  if (beg > n) beg = n;
  int s = 0;
  for (int i = beg; i < end; i++) s += hist[i];
  part[t] = s;
  __syncthreads();
  for (int off = 1; off < 1024; off <<= 1) {
    int v = (t >= off) ? part[t - off] : 0;
    __syncthreads();
    if (t >= off) part[t] += v;
    __syncthreads();
  }
  int run = (t > 0) ? part[t - 1] : 0;
  for (int i = beg; i < end; i++) { row_off[i] = run; run += hist[i]; }
  if (t == 0) row_off[n] = part[1023];
}

__global__ void scatter_kernel(const int* __restrict__ src, const int* __restrict__ dst,
                               const int* __restrict__ row_off, int* __restrict__ cur,
                               int* __restrict__ csr_src, int E) {
  int e = blockIdx.x * 256 + threadIdx.x;
  if (e < E) {
    int d = dst[e];
    int p = atomicAdd(&cur[d], 1);
    csr_src[row_off[d] + p] = src[e];
  }
}

// ======================= SAGE mean aggregation (wave per node) =======================
__global__ __launch_bounds__(256) void sage_agg_kernel(const float* __restrict__ h,
    const int* __restrict__ row_off, const int* __restrict__ csr_src,
    float* __restrict__ mean, int n) {
  int node = (blockIdx.x << 2) + (threadIdx.x >> 6);
  int lane = threadIdx.x & 63;
  if (node >= n) return;
  int beg = row_off[node], end = row_off[node + 1];
  float acc[5] = {0.f, 0.f, 0.f, 0.f, 0.f};
  for (int e = beg; e < end; e++) {
    const float* row = h + (size_t)csr_src[e] * HID;
    #pragma unroll
    for (int k = 0; k < 5; k++) acc[k] += row[lane + (k << 6)];
  }
  int deg = end - beg;
  float inv = 1.0f / (float)(deg > 0 ? deg : 1);
  float* o = mean + (size_t)node * HID;
  #pragma unroll
  for (int k = 0; k < 5; k++) o[lane + (k << 6)] = acc[k] * inv;
}

// ======================= GAT: per-(node,head) attention dots =======================
__global__ void gat_prep_kernel(const float* __restrict__ xh,
    const float* __restrict__ asrc, const float* __restrict__ adst,
    float* __restrict__ al, float* __restrict__ ar, int n) {
  int idx = blockIdx.x * 256 + threadIdx.x;
  if (idx >= n * HEADS) return;
  int node = idx >> 2, hh = idx & 3;
  const float* row = xh + (size_t)node * HID + hh * HDIM;
  const float* as = asrc + hh * HDIM;
  const float* ad = adst + hh * HDIM;
  float sl = 0.f, sr = 0.f;
  for (int d = 0; d < HDIM; d++) { float v = row[d]; sl += v * as[d]; sr += v * ad[d]; }
  al[idx] = sl;
  ar[idx] = sr;
}

// ======================= GAT aggregation: softmax + weighted sum + bias+BN+ReLU ===
__global__ __launch_bounds__(256) void gat_agg_kernel(const float* __restrict__ xh,
    const int* __restrict__ row_off, const int* __restrict__ csr_src,
    const float* __restrict__ al, const float* __restrict__ ar,
    const float* __restrict__ bias, const float* __restrict__ gamma,
    const float* __restrict__ beta, float* __restrict__ out, int n) {
  int node = (blockIdx.x << 2) + (threadIdx.x >> 6);
  int lane = threadIdx.x & 63;
  if (node >= n) return;
  int beg = row_off[node], end = row_off[node + 1];
  float arv[4], alv_i[4];
  #pragma unroll
  for (int hh = 0; hh < 4; hh++) { arv[hh] = ar[node * 4 + hh]; alv_i[hh] = al[node * 4 + hh]; }
  // pass 1: segment max (self loop included; every node has >=1 entry -> finite)
  float m[4];
  #pragma unroll
  for (int hh = 0; hh < 4; hh++) {
    float v = alv_i[hh] + arv[hh];
    m[hh] = v > 0.f ? v : NEG_SLOPE * v;
  }
  for (int e = beg + lane; e < end; e += 64) {
    int s = csr_src[e];
    #pragma unroll
    for (int hh = 0; hh < 4; hh++) {
      float v = al[s * 4 + hh] + arv[hh];
      v = v > 0.f ? v : NEG_SLOPE * v;
      m[hh] = fmaxf(m[hh], v);
    }
  }
  #pragma unroll
  for (int off = 1; off < 64; off <<= 1) {
    #pragma unroll
    for (int hh = 0; hh < 4; hh++) m[hh] = fmaxf(m[hh], __shfl_xor(m[hh], off));
  }
  // pass 2: exp, denominator, weighted feature sum (lanes parallel over feature dim)
  float den[4] = {0.f, 0.f, 0.f, 0.f};
  float num[5] = {0.f, 0.f, 0.f, 0.f, 0.f};
  int pos[5], hk[5];
  #pragma unroll
  for (int k = 0; k < 5; k++) { pos[k] = lane + (k << 6); hk[k] = pos[k] / HDIM; }
  for (int e = beg - 1; e < end; e++) {
    int s = (e < beg) ? node : csr_src[e];  // e == beg-1 -> self loop
    float ex[4];
    #pragma unroll
    for (int hh = 0; hh < 4; hh++) {
      float v = al[s * 4 + hh] + arv[hh];
      v = v > 0.f ? v : NEG_SLOPE * v;
      ex[hh] = expf(v - m[hh]);
      den[hh] += ex[hh];
    }
    const float* row = xh + (size_t)s * HID;
    #pragma unroll
    for (int k = 0; k < 5; k++) num[k] += ex[hk[k]] * row[pos[k]];
  }
  const float bnrs = 1.0f / sqrtf(1.0f + 1e-5f);
  float* o = out + (size_t)node * HID;
  #pragma unroll
  for (int k = 0; k < 5; k++) {
    int p = pos[k];
    float d = den[hk[k]];
    d = d > 1e-16f ? d : 1e-16f;
    float v = num[k] / d + bias[p];
    v = v * (gamma[p] * bnrs) + beta[p];
    o[p] = v > 0.f ? v : 0.f;
  }
}

// ======================= Tiled fp32 GEMM with fused epilogue =======================
// C[M x Nd] = act(BN(A1@W1 (+ A2@W2) + bias))
// tile: 128x64, BK=16, 256 threads, each thread 8x4 outputs (2x4 rows x 4 cols)
template<bool HAS2, bool HASBIAS, bool HASBN, bool RELU>
__global__ __launch_bounds__(256) void gemm_ep(
    const float* __restrict__ A1, const float* __restrict__ W1, int K1,
    const float* __restrict__ A2, const float* __restrict__ W2, int K2,
    const float* __restrict__ bias, const float* __restrict__ gamma,
    const float* __restrict__ beta,
    float* __restrict__ C, int M, int Nd) {
  __shared__ float As[16][132];  // transposed: As[k][m]
  __shared__ float Bs[16][68];
  int t = threadIdx.x;
  int tx = t & 15, ty = t >> 4;
  int bm = blockIdx.x * 128;
  int bn = blockIdx.y * 64;
  float acc[2][4][4];
  #pragma unroll
  for (int ri = 0; ri < 2; ri++)
    #pragma unroll
    for (int i = 0; i < 4; i++)
      #pragma unroll
      for (int j = 0; j < 4; j++) acc[ri][i][j] = 0.f;

  const int npass = HAS2 ? 2 : 1;
  for (int pass = 0; pass < npass; ++pass) {
    const float* A = (pass == 0) ? A1 : A2;
    const float* W = (pass == 0) ? W1 : W2;
    int K = (pass == 0) ? K1 : K2;
    for (int k0 = 0; k0 < K; k0 += 16) {
      // stage A tile (128 rows x 16 k), transposed into LDS
      #pragma unroll
      for (int p = 0; p < 2; p++) {
        int row = p * 64 + (t >> 2);
        int col = (t & 3) * 4;
        int gr = bm + row;
        gr = gr < M ? gr : M - 1;
        float4 v = *reinterpret_cast<const float4*>(A + (size_t)gr * K + k0 + col);
        As[col + 0][row] = v.x;
        As[col + 1][row] = v.y;
        As[col + 2][row] = v.z;
        As[col + 3][row] = v.w;
      }
      // stage B tile (16 k x 64 cols)
      {
        int row = t >> 4;
        int col = (t & 15) * 4;
        int gc = bn + col;
        float4 v;
        if (gc < Nd) v = *reinterpret_cast<const float4*>(W + (size_t)(k0 + row) * Nd + gc);
        else v = make_float4(0.f, 0.f, 0.f, 0.f);
        *reinterpret_cast<float4*>(&Bs[row][col]) = v;
      }
      __syncthreads();
      #pragma unroll
      for (int kk = 0; kk < 16; kk++) {
        float a[2][4], b[4];
        *reinterpret_cast<float4*>(a[0]) = *reinterpret_cast<const float4*>(&As[kk][ty * 4]);
        *reinterpret_cast<float4*>(a[1]) = *reinterpret_cast<const float4*>(&As[kk][64 + ty * 4]);
        *reinterpret_cast<float4*>(b) = *reinterpret_cast<const float4*>(&Bs[kk][tx * 4]);
        #pragma unroll
        for (int ri = 0; ri < 2; ri++)
          #pragma unroll
          for (int i = 0; i < 4; i++)
            #pragma unroll
            for (int j = 0; j < 4; j++) acc[ri][i][j] += a[ri][i] * b[j];
      }
      __syncthreads();
    }
  }

  const float bnrs = 1.0f / sqrtf(1.0f + 1e-5f);
  #pragma unroll
  for (int ri = 0; ri < 2; ri++) {
    #pragma unroll
    for (int i = 0; i < 4; i++) {
      int r = bm + ri * 64 + ty * 4 + i;
      if (r >= M) continue;
      int cbase = bn + tx * 4;
      float v[4];
      #pragma unroll
      for (int j = 0; j < 4; j++) {
        v[j] = acc[ri][i][j];
        int c = cbase + j;
        if (c < Nd) {
          if (HASBIAS) v[j] += bias[c];
          if (HASBN) v[j] = v[j] * (gamma[c] * bnrs) + beta[c];
          if (RELU) v[j] = v[j] > 0.f ? v[j] : 0.f;
        }
      }
      if (cbase + 3 < Nd) {
        float4 q;
        q.x = v[0]; q.y = v[1]; q.z = v[2]; q.w = v[3];
        *reinterpret_cast<float4*>(C + (size_t)r * Nd + cbase) = q;
      } else {
        #pragma unroll
        for (int j = 0; j < 4; j++)
          if (cbase + j < Nd) C[(size_t)r * Nd + cbase + j] = v[j];
      }
    }
  }
}

// ======================= classifier second layer: [N,160] @ [160,2] + b ============
__global__ void cls2_kernel(const float* __restrict__ tbuf, const float* __restrict__ w2,
                            const float* __restrict__ b2, float* __restrict__ out, int M) {
  int r = blockIdx.x * 256 + threadIdx.x;
  if (r >= M) return;
  const float* row = tbuf + (size_t)r * 160;
  float a0 = b2[0], a1 = b2[1];
  for (int d = 0; d < 160; d++) {
    float v = row[d];
    a0 += v * w2[2 * d];
    a1 += v * w2[2 * d + 1];
  }
  out[2 * r] = a0;
  out[2 * r + 1] = a1;
}

// ======================= launch =======================
extern "C" void kernel_launch(void* const* d_in, const int* in_sizes, int n_in,
                              void* d_out, int out_size, void* d_ws, size_t ws_size,
                              hipStream_t stream) {
  const float* x    = (const float*)d_in[0];
  const int*   ei   = (const int*)d_in[1];
  const float* w_in = (const float*)d_in[2];
  const float* b_in = (const float*)d_in[3];
  const float* s0wl = (const float*)d_in[4];
  const float* s0bl = (const float*)d_in[5];
  const float* s0wr = (const float*)d_in[6];
  const float* g1w  = (const float*)d_in[7];
  const float* g1as = (const float*)d_in[8];
  const float* g1ad = (const float*)d_in[9];
  const float* g1b  = (const float*)d_in[10];
  const float* s2wl = (const float*)d_in[11];
  const float* s2bl = (const float*)d_in[12];
  const float* s2wr = (const float*)d_in[13];
  const float* g3w  = (const float*)d_in[14];
  const float* g3as = (const float*)d_in[15];
  const float* g3ad = (const float*)d_in[16];
  const float* g3b  = (const float*)d_in[17];
  const float* bng  = (const float*)d_in[18];
  const float* bnb  = (const float*)d_in[19];
  const float* cw1  = (const float*)d_in[20];
  const float* cb1  = (const float*)d_in[21];
  const float* cw2  = (const float*)d_in[22];
  const float* cb2  = (const float*)d_in[23];

  char* ws = (char*)d_ws;
  size_t off = 0;
  auto alloc = [&](size_t bytes) {
    void* p = ws + off;
    off += (bytes + 255) & ~(size_t)255;
    return p;
  };
  float* B0      = (float*)alloc((size_t)N_NODES * HID * 4);
  float* B1      = (float*)alloc((size_t)N_NODES * HID * 4);
  float* al      = (float*)alloc((size_t)N_NODES * HEADS * 4);
  float* ar      = (float*)alloc((size_t)N_NODES * HEADS * 4);
  int*   row_off = (int*)alloc((size_t)(N_NODES + 1) * 4);
  int*   hist    = (int*)alloc((size_t)N_NODES * 4);
  int*   cur     = (int*)alloc((size_t)N_NODES * 4);
  int*   csr_src = (int*)alloc((size_t)N_EDGES * 4);

  float* outp = (float*)d_out;                 // [N,2]
  float* emb  = outp + (size_t)N_NODES * 2;    // [N,320] (also used as 3rd big buffer)

  const int* srcp = ei;
  const int* dstp = ei + N_EDGES;

  // CSR build
  hipMemsetAsync(hist, 0, N_NODES * 4, stream);
  hipMemsetAsync(cur, 0, N_NODES * 4, stream);
  hist_kernel<<<(N_EDGES + 255) / 256, 256, 0, stream>>>(dstp, hist, N_EDGES);
  scan_kernel<<<1, 1024, 0, stream>>>(hist, row_off, N_NODES);
  scatter_kernel<<<(N_EDGES + 255) / 256, 256, 0, stream>>>(srcp, dstp, row_off, cur, csr_src, N_EDGES);

  dim3 blk(256);
  dim3 g5((N_NODES + 127) / 128, 5);
  dim3 g3((N_NODES + 127) / 128, 3);
  int aggBlocks = (N_NODES + 3) / 4;

  // input layer: h0 = relu(x @ w_in + b_in) -> B0
  gemm_ep<false, true, false, true><<<g5, blk, 0, stream>>>(
      x, w_in, DIM_IN, nullptr, nullptr, 0, b_in, nullptr, nullptr, B0, N_NODES, HID);

  // SAGE0: mean(B0)->B1 ; h1 = relu(BN0(mean@wl + h0@wr + bl)) -> emb
  sage_agg_kernel<<<aggBlocks, blk, 0, stream>>>(B0, row_off, csr_src, B1, N_NODES);
  gemm_ep<true, true, true, true><<<g5, blk, 0, stream>>>(
      B1, s0wl, HID, B0, s0wr, HID, s0bl, bng + 0 * HID, bnb + 0 * HID, emb, N_NODES, HID);

  // GAT1: xh = emb @ g1w -> B0 ; attn ; h2 -> B1
  gemm_ep<false, false, false, false><<<g5, blk, 0, stream>>>(
      emb, g1w, HID, nullptr, nullptr, 0, nullptr, nullptr, nullptr, B0, N_NODES, HID);
  gat_prep_kernel<<<(N_NODES * HEADS + 255) / 256, blk, 0, stream>>>(B0, g1as, g1ad, al, ar, N_NODES);
  gat_agg_kernel<<<aggBlocks, blk, 0, stream>>>(
      B0, row_off, csr_src, al, ar, g1b, bng + 1 * HID, bnb + 1 * HID, B1, N_NODES);

  // SAGE2: mean(B1)->B0 ; h3 = relu(BN2(mean@wl + h2@wr + bl)) -> emb
  sage_agg_kernel<<<aggBlocks, blk, 0, stream>>>(B1, row_off, csr_src, B0, N_NODES);
  gemm_ep<true, true, true, true><<<g5, blk, 0, stream>>>(
      B0, s2wl, HID, B1, s2wr, HID, s2bl, bng + 2 * HID, bnb + 2 * HID, emb, N_NODES, HID);

  // GAT3: xh = emb @ g3w -> B0 ; attn ; embeddings -> emb (d_out region)
  gemm_ep<false, false, false, false><<<g5, blk, 0, stream>>>(
      emb, g3w, HID, nullptr, nullptr, 0, nullptr, nullptr, nullptr, B0, N_NODES, HID);
  gat_prep_kernel<<<(N_NODES * HEADS + 255) / 256, blk, 0, stream>>>(B0, g3as, g3ad, al, ar, N_NODES);
  gat_agg_kernel<<<aggBlocks, blk, 0, stream>>>(
      B0, row_off, csr_src, al, ar, g3b, bng + 3 * HID, bnb + 3 * HID, emb, N_NODES);

  // classifier: t = relu(emb@cw1 + cb1) -> B1 ; out = t@cw2 + cb2 -> d_out[0:2N]
  gemm_ep<false, true, false, true><<<g3, blk, 0, stream>>>(
      emb, cw1, HID, nullptr, nullptr, 0, cb1, nullptr, nullptr, B1, N_NODES, 160);
  cls2_kernel<<<(N_NODES + 255) / 256, blk, 0, stream>>>(B1, cw2, cb2, outp, N_NODES);
}

// Round 4
// 1539.679 us; speedup vs baseline: 1.2222x; 1.2222x over previous
//
#include <hip/hip_runtime.h>
#include <cstdint>

#define MN 50000
#define EN 800000
#define HID 320
#define HEADS 4
#define HDIM 80
#define NEG_SLOPE 0.2f

typedef __attribute__((ext_vector_type(4))) float f32x4;
typedef __attribute__((ext_vector_type(8))) short short8v;

__device__ __forceinline__ unsigned short f2bf(float f){
  unsigned u = __float_as_uint(f);
  return (unsigned short)((u + 0x7fffu + ((u >> 16) & 1u)) >> 16);  // RNE
}
__device__ __forceinline__ float bf2f(unsigned short s){
  return __uint_as_float(((unsigned)s) << 16);
}
__device__ __forceinline__ void gldlds16(const void* g, void* l){
  __builtin_amdgcn_global_load_lds((const __attribute__((address_space(1))) void*)g,
                                   (__attribute__((address_space(3))) void*)l, 16, 0, 0);
}

// ======================= CSR build (counting sort by dst) =======================
__global__ void hist_kernel(const int* __restrict__ dst, int* __restrict__ hist, int E) {
  int e = blockIdx.x * 256 + threadIdx.x;
  if (e < E) atomicAdd(&hist[dst[e]], 1);
}

__global__ __launch_bounds__(1024) void scan_kernel(const int* __restrict__ hist,
                                                    int* __restrict__ row_off, int n) {
  __shared__ int part[1024];
  int t = threadIdx.x;
  int chunk = (n + 1023) >> 10;
  int beg = t * chunk, end = beg + chunk;
  if (end > n) end = n;
  if (beg > n) beg = n;
  int s = 0;
  for (int i = beg; i < end; i++) s += hist[i];
  part[t] = s;
  __syncthreads();
  for (int off = 1; off < 1024; off <<= 1) {
    int v = (t >= off) ? part[t - off] : 0;
    __syncthreads();
    if (t >= off) part[t] += v;
    __syncthreads();
  }
  int run = (t > 0) ? part[t - 1] : 0;
  for (int i = beg; i < end; i++) { row_off[i] = run; run += hist[i]; }
  if (t == 0) row_off[n] = part[1023];
}

__global__ void scatter_kernel(const int* __restrict__ src, const int* __restrict__ dst,
                               const int* __restrict__ row_off, int* __restrict__ cur,
                               int* __restrict__ csr_src, int E) {
  int e = blockIdx.x * 256 + threadIdx.x;
  if (e < E) {
    int d = dst[e];
    int p = atomicAdd(&cur[d], 1);
    csr_src[row_off[d] + p] = src[e];
  }
}

// ======================= weight prep: transpose + bf16x2 split + chunk swizzle ==
// dst tile layout: [kt][col][chunk'][8 elems] bf16 ; chunk = chunk' ^ ((col>>1)&3)
// stacked K' = 3K: W' = [Whi ; Whi ; Wlo]  (pairs with A' = [Ahi | Alo | Ahi])
__global__ void wprep(const float* __restrict__ W, unsigned short* __restrict__ dst,
                      int K, int Nsz, int total) {
  int idx = blockIdx.x * 256 + threadIdx.x;
  if (idx >= total) return;
  int j = idx & 7;
  int c1 = (idx >> 3) & 3;
  int rest = idx >> 5;
  int col = rest % Nsz;
  int kt = rest / Nsz;
  int chunk = c1 ^ ((col >> 1) & 3);
  int kp = kt * 32 + chunk * 8 + j;
  int seg = kp / K;
  int k = kp - seg * K;
  float v = W[(size_t)k * Nsz + col];
  unsigned short h = f2bf(v);
  unsigned short o = (seg == 2) ? f2bf(v - bf2f(h)) : h;
  dst[(size_t)kt * Nsz * 32 + (size_t)col * 32 + c1 * 8 + j] = o;
}

// ======================= stacked-K bf16 MFMA GEMM ==============================
// C[M x N] = act(BN(A1'@W1' (+ A2'@W2') + bias)), A planes [M][640] bf16 (hi|lo)
// BM=96, BN=N=CW*80, 2 row-waves x CW col-waves, 3x5 16x16x32 frags per wave.
// MODE: 0 = f32 raw ; 1 = f32 bias+relu ; 2 = split bias+relu ; 3 = split bias+BN+relu
template<int CW, bool SRCF32, int SEGT, int NPASS, int MODE>
__global__ __launch_bounds__(128 * CW, 4) void mfma_gemm(
    const char* __restrict__ A1, const char* __restrict__ A2,
    const char* __restrict__ Wq,
    const float* __restrict__ bias, const float* __restrict__ gamma,
    const float* __restrict__ beta, void* __restrict__ outp, int M)
{
  static_assert(!SRCF32 || CW == 4, "");
  constexpr int TPB = 128 * CW;
  constexpr int N = CW * 80;
  constexpr int NT = NPASS * 3 * SEGT;
  constexpr int TILEB = N * 64;
  constexpr int AIT = (384 + TPB - 1) / TPB;
  __shared__ __align__(16) char ldsA[2 * 7680];
  __shared__ __align__(16) char ldsB[2 * TILEB];
  const int tid = threadIdx.x;
  const int lane = tid & 63;
  const int w = tid >> 6;
  const int rw = w & 1, cwv = w >> 1;
  const int bm = blockIdx.x * 96;
  const int kc = (lane >> 4) & 3;
  const int l15 = lane & 15;

  int aoff[3], boff[5];
  #pragma unroll
  for (int fr = 0; fr < 3; fr++) aoff[fr] = (rw * 48 + fr * 16 + l15) * 80 + kc * 16;
  #pragma unroll
  for (int cf = 0; cf < 5; cf++) {
    int col = cwv * 80 + cf * 16 + l15;
    boff[cf] = col * 64 + ((kc ^ ((col >> 1) & 3)) << 4);
  }

  f32x4 acc[3][5];
  #pragma unroll
  for (int i = 0; i < 3; i++)
    #pragma unroll
    for (int j = 0; j < 5; j++) { f32x4 z = {0.f, 0.f, 0.f, 0.f}; acc[i][j] = z; }

  f32x4 areg[AIT][2];
  auto issueA = [&](int t) -> bool {
    int pass = 0, tt = t;
    if constexpr (NPASS == 2) { pass = t / (3 * SEGT); tt = t - pass * (3 * SEGT); }
    int seg = tt / SEGT;
    int kk = tt - seg * SEGT;
    const char* __restrict__ base = pass ? A2 : A1;
    #pragma unroll
    for (int it = 0; it < AIT; it++) {
      int s = tid + it * TPB;
      if (s < 384) {
        int row = s >> 2, c = s & 3;
        int r = bm + row; if (r >= M) r = M - 1;
        if constexpr (SRCF32) {
          const char* p = base + (size_t)r * 512 + kk * 128 + c * 32;
          areg[it][0] = *(const f32x4*)p;
          areg[it][1] = *(const f32x4*)(p + 16);
        } else {
          const char* p = base + (size_t)r * 1280 + (seg == 1 ? 640 : 0) + kk * 64 + c * 16;
          areg[it][0] = *(const f32x4*)p;
        }
      }
    }
    return seg == 1;
  };
  auto writeA = [&](int buf, bool lo) {
    #pragma unroll
    for (int it = 0; it < AIT; it++) {
      int s = tid + it * TPB;
      if (s < 384) {
        int row = s >> 2, c = s & 3;
        char* d = &ldsA[buf * 7680 + row * 80 + c * 16];  // 80B pitch: 2-way banks = free
        if constexpr (SRCF32) {
          short8v v;
          #pragma unroll
          for (int j = 0; j < 8; j++) {
            float f = (j < 4) ? areg[it][0][j] : areg[it][1][j - 4];
            unsigned short h = f2bf(f);
            unsigned short o = lo ? f2bf(f - bf2f(h)) : h;
            v[j] = (short)o;
          }
          *(short8v*)d = v;
        } else {
          f32x4 t4 = areg[it][0];
          *(short8v*)d = *(short8v*)&t4;
        }
      }
    }
  };
  auto issueB = [&](int t, int buf) {
    const char* __restrict__ src = Wq + (size_t)t * TILEB;
    for (int s = tid; s < N * 4; s += TPB)
      gldlds16(src + (size_t)s * 16, &ldsB[buf * TILEB + s * 16]);
  };

  bool plo = issueA(0);
  issueB(0, 0);
  writeA(0, plo);
  __syncthreads();

  for (int t = 0; t < NT; ++t) {
    int curb = t & 1, nxt = curb ^ 1;
    bool lo = false;
    if (t + 1 < NT) { lo = issueA(t + 1); issueB(t + 1, nxt); }
    short8v af0 = *(const short8v*)&ldsA[curb * 7680 + aoff[0]];
    short8v af1 = *(const short8v*)&ldsA[curb * 7680 + aoff[1]];
    short8v af2 = *(const short8v*)&ldsA[curb * 7680 + aoff[2]];
    #pragma unroll
    for (int cf = 0; cf < 5; cf++) {
      short8v bv = *(const short8v*)&ldsB[curb * TILEB + boff[cf]];
      acc[0][cf] = __builtin_amdgcn_mfma_f32_16x16x32_bf16(af0, bv, acc[0][cf], 0, 0, 0);
      acc[1][cf] = __builtin_amdgcn_mfma_f32_16x16x32_bf16(af1, bv, acc[1][cf], 0, 0, 0);
      acc[2][cf] = __builtin_amdgcn_mfma_f32_16x16x32_bf16(af2, bv, acc[2][cf], 0, 0, 0);
    }
    if (t + 1 < NT) writeA(nxt, lo);
    __syncthreads();
  }

  const float bnrs = 0.99999500003749971f;  // 1/sqrt(1+1e-5)
  #pragma unroll
  for (int fr = 0; fr < 3; fr++) {
    int rbase = bm + rw * 48 + fr * 16 + (lane >> 4) * 4;
    #pragma unroll
    for (int cf = 0; cf < 5; cf++) {
      int col = cwv * 80 + cf * 16 + l15;
      float bi = 0.f, sc = 1.f, be = 0.f;
      if constexpr (MODE >= 1) bi = bias[col];
      if constexpr (MODE == 3) { sc = gamma[col] * bnrs; be = beta[col]; }
      #pragma unroll
      for (int rg = 0; rg < 4; rg++) {
        int r = rbase + rg;
        if (r < M) {
          float v = acc[fr][cf][rg];
          if constexpr (MODE >= 1) v += bi;
          if constexpr (MODE == 3) v = v * sc + be;
          if constexpr (MODE >= 1) v = v > 0.f ? v : 0.f;
          if constexpr (MODE >= 2) {
            unsigned short h = f2bf(v);
            unsigned short g = f2bf(v - bf2f(h));
            unsigned short* o = (unsigned short*)outp;
            o[(size_t)r * 640 + col] = h;
            o[(size_t)r * 640 + 320 + col] = g;
          } else {
            ((float*)outp)[(size_t)r * N + col] = v;
          }
        }
      }
    }
  }
}

// ======================= SAGE mean aggregation on split planes ==================
// half-wave (32 lanes) per node; rows are [320] dwords: hi dwords 0..159, lo 160..319
__global__ __launch_bounds__(256) void sage_agg_split(const unsigned* __restrict__ hp,
    const int* __restrict__ row_off, const int* __restrict__ csr_src,
    unsigned* __restrict__ outp, int n) {
  int node = blockIdx.x * 8 + (threadIdx.x >> 5);
  int lane = threadIdx.x & 31;
  if (node >= n) return;
  int beg = row_off[node], end = row_off[node + 1];
  float s0[5] = {0,0,0,0,0}, s1[5] = {0,0,0,0,0};
  float t0[5] = {0,0,0,0,0}, t1[5] = {0,0,0,0,0};
  for (int e = beg; e < end; e++) {
    const unsigned* row = hp + (size_t)csr_src[e] * 320;
    #pragma unroll
    for (int k = 0; k < 5; k++) {
      unsigned dh = row[lane + 32 * k];
      unsigned dl = row[160 + lane + 32 * k];
      s0[k] += bf2f((unsigned short)dh);
      s1[k] += bf2f((unsigned short)(dh >> 16));
      t0[k] += bf2f((unsigned short)dl);
      t1[k] += bf2f((unsigned short)(dl >> 16));
    }
  }
  int deg = end - beg;
  float inv = 1.0f / (float)(deg > 0 ? deg : 1);
  unsigned* orow = outp + (size_t)node * 320;
  #pragma unroll
  for (int k = 0; k < 5; k++) {
    float v0 = (s0[k] + t0[k]) * inv;
    float v1 = (s1[k] + t1[k]) * inv;
    unsigned short h0 = f2bf(v0), h1 = f2bf(v1);
    unsigned short g0 = f2bf(v0 - bf2f(h0)), g1 = f2bf(v1 - bf2f(h1));
    orow[lane + 32 * k] = (unsigned)h0 | ((unsigned)h1 << 16);
    orow[160 + lane + 32 * k] = (unsigned)g0 | ((unsigned)g1 << 16);
  }
}

// ======================= GAT: per-(node,head) attention dots ====================
__global__ void gat_prep(const float* __restrict__ xh,
    const float* __restrict__ asrc, const float* __restrict__ adst,
    float* __restrict__ al, float* __restrict__ ar, int n) {
  int idx = blockIdx.x * 256 + threadIdx.x;
  if (idx >= n * HEADS) return;
  int node = idx >> 2, hh = idx & 3;
  const float* row = xh + (size_t)node * HID + hh * HDIM;
  const float* as = asrc + hh * HDIM;
  const float* ad = adst + hh * HDIM;
  float sl = 0.f, sr = 0.f;
  for (int d = 0; d < HDIM; d++) { float v = row[d]; sl += v * as[d]; sr += v * ad[d]; }
  al[idx] = sl;
  ar[idx] = sr;
}

// ======================= GAT aggregation: softmax + weighted sum + epilogue =====
template<bool F32OUT>
__global__ __launch_bounds__(256) void gat_agg(const float* __restrict__ xh,
    const int* __restrict__ row_off, const int* __restrict__ csr_src,
    const float* __restrict__ al, const float* __restrict__ ar,
    const float* __restrict__ bias, const float* __restrict__ gamma,
    const float* __restrict__ beta, unsigned short* __restrict__ outS,
    float* __restrict__ outF, int n) {
  int node = (blockIdx.x << 2) + (threadIdx.x >> 6);
  int lane = threadIdx.x & 63;
  if (node >= n) return;
  int beg = row_off[node], end = row_off[node + 1];
  float arv[4], alv_i[4];
  #pragma unroll
  for (int hh = 0; hh < 4; hh++) { arv[hh] = ar[node * 4 + hh]; alv_i[hh] = al[node * 4 + hh]; }
  float m[4];
  #pragma unroll
  for (int hh = 0; hh < 4; hh++) {
    float v = alv_i[hh] + arv[hh];
    m[hh] = v > 0.f ? v : NEG_SLOPE * v;   // self-loop term
  }
  for (int e = beg + lane; e < end; e += 64) {
    int s = csr_src[e];
    #pragma unroll
    for (int hh = 0; hh < 4; hh++) {
      float v = al[s * 4 + hh] + arv[hh];
      v = v > 0.f ? v : NEG_SLOPE * v;
      m[hh] = fmaxf(m[hh], v);
    }
  }
  #pragma unroll
  for (int off = 1; off < 64; off <<= 1) {
    #pragma unroll
    for (int hh = 0; hh < 4; hh++) m[hh] = fmaxf(m[hh], __shfl_xor(m[hh], off));
  }
  float den[4] = {0.f, 0.f, 0.f, 0.f};
  float num[5] = {0.f, 0.f, 0.f, 0.f, 0.f};
  int pos[5], hk[5];
  #pragma unroll
  for (int k = 0; k < 5; k++) { pos[k] = lane + (k << 6); hk[k] = pos[k] / HDIM; }
  for (int e = beg - 1; e < end; e++) {
    int s = (e < beg) ? node : csr_src[e];  // e == beg-1 -> self loop
    float ex[4];
    #pragma unroll
    for (int hh = 0; hh < 4; hh++) {
      float v = al[s * 4 + hh] + arv[hh];
      v = v > 0.f ? v : NEG_SLOPE * v;
      ex[hh] = expf(v - m[hh]);
      den[hh] += ex[hh];
    }
    const float* row = xh + (size_t)s * HID;
    #pragma unroll
    for (int k = 0; k < 5; k++) num[k] += ex[hk[k]] * row[pos[k]];
  }
  const float bnrs = 0.99999500003749971f;
  #pragma unroll
  for (int k = 0; k < 5; k++) {
    int p = pos[k];
    float d = den[hk[k]];
    d = d > 1e-16f ? d : 1e-16f;
    float v = num[k] / d + bias[p];
    v = v * (gamma[p] * bnrs) + beta[p];
    v = v > 0.f ? v : 0.f;
    unsigned short h = f2bf(v);
    outS[(size_t)node * 640 + p] = h;
    outS[(size_t)node * 640 + 320 + p] = f2bf(v - bf2f(h));
    if constexpr (F32OUT) outF[(size_t)node * 320 + p] = v;
  }
}

// ======================= classifier second layer ================================
__global__ void cls2_kernel(const float* __restrict__ tbuf, const float* __restrict__ w2,
                            const float* __restrict__ b2, float* __restrict__ out, int M) {
  int r = blockIdx.x * 256 + threadIdx.x;
  if (r >= M) return;
  const float* row = tbuf + (size_t)r * 160;
  float a0 = b2[0], a1 = b2[1];
  for (int d = 0; d < 160; d++) {
    float v = row[d];
    a0 += v * w2[2 * d];
    a1 += v * w2[2 * d + 1];
  }
  out[2 * r] = a0;
  out[2 * r + 1] = a1;
}

// ======================= launch =======================
extern "C" void kernel_launch(void* const* d_in, const int* in_sizes, int n_in,
                              void* d_out, int out_size, void* d_ws, size_t ws_size,
                              hipStream_t stream) {
  const float* x    = (const float*)d_in[0];
  const int*   ei   = (const int*)d_in[1];
  const float* w_in = (const float*)d_in[2];
  const float* b_in = (const float*)d_in[3];
  const float* s0wl = (const float*)d_in[4];
  const float* s0bl = (const float*)d_in[5];
  const float* s0wr = (const float*)d_in[6];
  const float* g1w  = (const float*)d_in[7];
  const float* g1as = (const float*)d_in[8];
  const float* g1ad = (const float*)d_in[9];
  const float* g1b  = (const float*)d_in[10];
  const float* s2wl = (const float*)d_in[11];
  const float* s2bl = (const float*)d_in[12];
  const float* s2wr = (const float*)d_in[13];
  const float* g3w  = (const float*)d_in[14];
  const float* g3as = (const float*)d_in[15];
  const float* g3ad = (const float*)d_in[16];
  const float* g3b  = (const float*)d_in[17];
  const float* bng  = (const float*)d_in[18];
  const float* bnb  = (const float*)d_in[19];
  const float* cw1  = (const float*)d_in[20];
  const float* cb1  = (const float*)d_in[21];
  const float* cw2  = (const float*)d_in[22];
  const float* cb2  = (const float*)d_in[23];

  char* ws = (char*)d_ws;
  size_t off = 0;
  auto alloc = [&](size_t b) {
    void* p = (void*)(ws + off);
    off += (b + 255) & ~(size_t)255;
    return p;
  };
  const size_t SB = (size_t)MN * 1280;        // one split-plane matrix [M][640] bf16
  char* S0 = (char*)alloc(SB);
  char* S1 = (char*)alloc(SB);
  char* S2 = (char*)alloc(SB);
  char* WQ = (char*)alloc(4239360);
  float* al      = (float*)alloc((size_t)MN * HEADS * 4);
  float* ar      = (float*)alloc((size_t)MN * HEADS * 4);
  int*   row_off = (int*)alloc((size_t)(MN + 1) * 4);
  int*   hist    = (int*)alloc((size_t)MN * 4);
  int*   curw    = (int*)alloc((size_t)MN * 4);
  int*   csr     = (int*)alloc((size_t)EN * 4);

  float* outp = (float*)d_out;
  float* emb  = outp + (size_t)MN * 2;        // [M,320] fp32; doubles as xh1 scratch

  const int* srcp = ei;
  const int* dstp = ei + EN;

  // CSR
  hipMemsetAsync(hist, 0, MN * 4, stream);
  hipMemsetAsync(curw, 0, MN * 4, stream);
  hist_kernel<<<(EN + 255) / 256, 256, 0, stream>>>(dstp, hist, EN);
  scan_kernel<<<1, 1024, 0, stream>>>(hist, row_off, MN);
  scatter_kernel<<<(EN + 255) / 256, 256, 0, stream>>>(srcp, dstp, row_off, curw, csr, EN);

  // weight prep (stacked+transposed+split+swizzled): tile = Nsz*64 bytes
  char* wq_in = WQ + 0;        // 12 tiles of 20480
  char* wq_s0 = WQ + 245760;   // 60 tiles (wl 30 | wr 30)
  char* wq_g1 = WQ + 1474560;  // 30
  char* wq_s2 = WQ + 2088960;  // 60
  char* wq_g3 = WQ + 3317760;  // 30
  char* wq_cl = WQ + 3932160;  // 30 tiles of 10240
  int tot = 12 * 320 * 32;
  wprep<<<(tot + 255) / 256, 256, 0, stream>>>(w_in, (unsigned short*)wq_in, 128, 320, tot);
  tot = 30 * 320 * 32;
  wprep<<<(tot + 255) / 256, 256, 0, stream>>>(s0wl, (unsigned short*)wq_s0, 320, 320, tot);
  wprep<<<(tot + 255) / 256, 256, 0, stream>>>(s0wr, (unsigned short*)(wq_s0 + 614400), 320, 320, tot);
  wprep<<<(tot + 255) / 256, 256, 0, stream>>>(g1w,  (unsigned short*)wq_g1, 320, 320, tot);
  wprep<<<(tot + 255) / 256, 256, 0, stream>>>(s2wl, (unsigned short*)wq_s2, 320, 320, tot);
  wprep<<<(tot + 255) / 256, 256, 0, stream>>>(s2wr, (unsigned short*)(wq_s2 + 614400), 320, 320, tot);
  wprep<<<(tot + 255) / 256, 256, 0, stream>>>(g3w,  (unsigned short*)wq_g3, 320, 320, tot);
  tot = 30 * 160 * 32;
  wprep<<<(tot + 255) / 256, 256, 0, stream>>>(cw1, (unsigned short*)wq_cl, 320, 160, tot);

  const int gx = (MN + 95) / 96;   // 521
  const int ga = (MN + 3) / 4;
  const int gs = (MN + 7) / 8;

  // h0 = relu(x@w_in + b_in)  -> split S0
  mfma_gemm<4, true, 4, 1, 2><<<gx, 512, 0, stream>>>(
      (const char*)x, nullptr, wq_in, b_in, nullptr, nullptr, S0, MN);
  // SAGE0
  sage_agg_split<<<gs, 256, 0, stream>>>((const unsigned*)S0, row_off, csr, (unsigned*)S1, MN);
  mfma_gemm<4, false, 10, 2, 3><<<gx, 512, 0, stream>>>(
      S1, S0, wq_s0, s0bl, bng, bnb, S2, MN);
  // GAT1: xh1 -> emb region (fp32 scratch), result split -> S0
  mfma_gemm<4, false, 10, 1, 0><<<gx, 512, 0, stream>>>(
      S2, nullptr, wq_g1, nullptr, nullptr, nullptr, emb, MN);
  gat_prep<<<(MN * HEADS + 255) / 256, 256, 0, stream>>>(emb, g1as, g1ad, al, ar, MN);
  gat_agg<false><<<ga, 256, 0, stream>>>(
      emb, row_off, csr, al, ar, g1b, bng + 320, bnb + 320, (unsigned short*)S0, nullptr, MN);
  // SAGE2
  sage_agg_split<<<gs, 256, 0, stream>>>((const unsigned*)S0, row_off, csr, (unsigned*)S1, MN);
  mfma_gemm<4, false, 10, 2, 3><<<gx, 512, 0, stream>>>(
      S1, S0, wq_s2, s2bl, bng + 640, bnb + 640, S2, MN);
  // GAT3: xh3 -> S0 (fp32), emb fp32 -> d_out, split -> S1
  mfma_gemm<4, false, 10, 1, 0><<<gx, 512, 0, stream>>>(
      S2, nullptr, wq_g3, nullptr, nullptr, nullptr, S0, MN);
  gat_prep<<<(MN * HEADS + 255) / 256, 256, 0, stream>>>((const float*)S0, g3as, g3ad, al, ar, MN);
  gat_agg<true><<<ga, 256, 0, stream>>>(
      (const float*)S0, row_off, csr, al, ar, g3b, bng + 960, bnb + 960,
      (unsigned short*)S1, emb, MN);
  // classifier
  mfma_gemm<2, false, 10, 1, 1><<<gx, 256, 0, stream>>>(
      S1, nullptr, wq_cl, cb1, nullptr, nullptr, S2, MN);
  cls2_kernel<<<(MN + 255) / 256, 256, 0, stream>>>((const float*)S2, cw2, cb2, outp, MN);
}

// Round 10
// 1501.376 us; speedup vs baseline: 1.2534x; 1.0255x over previous
//
#include <hip/hip_runtime.h>
#include <cstdint>

#define MN 50000
#define EN 800000
#define HID 320
#define HEADS 4
#define HDIM 80
#define NEG_SLOPE 0.2f

typedef __attribute__((ext_vector_type(4))) float f32x4;
typedef __attribute__((ext_vector_type(8))) short short8v;

__device__ __forceinline__ unsigned short f2bf(float f){
  unsigned u = __float_as_uint(f);
  return (unsigned short)((u + 0x7fffu + ((u >> 16) & 1u)) >> 16);  // RNE
}
__device__ __forceinline__ float bf2f(unsigned short s){
  return __uint_as_float(((unsigned)s) << 16);
}
__device__ __forceinline__ void gldlds16(const void* g, void* l){
  __builtin_amdgcn_global_load_lds((const __attribute__((address_space(1))) void*)g,
                                   (__attribute__((address_space(3))) void*)l, 16, 0, 0);
}

// ======================= CSR build (counting sort by dst) =======================
__global__ void hist_kernel(const int* __restrict__ dst, int* __restrict__ hist, int E) {
  int e = blockIdx.x * 256 + threadIdx.x;
  if (e < E) atomicAdd(&hist[dst[e]], 1);
}

__global__ __launch_bounds__(1024) void scan_kernel(const int* __restrict__ hist,
                                                    int* __restrict__ row_off, int n) {
  __shared__ int part[1024];
  int t = threadIdx.x;
  int chunk = (n + 1023) >> 10;
  int beg = t * chunk, end = beg + chunk;
  if (end > n) end = n;
  if (beg > n) beg = n;
  int s = 0;
  for (int i = beg; i < end; i++) s += hist[i];
  part[t] = s;
  __syncthreads();
  for (int off = 1; off < 1024; off <<= 1) {
    int v = (t >= off) ? part[t - off] : 0;
    __syncthreads();
    if (t >= off) part[t] += v;
    __syncthreads();
  }
  int run = (t > 0) ? part[t - 1] : 0;
  for (int i = beg; i < end; i++) { row_off[i] = run; run += hist[i]; }
  if (t == 0) row_off[n] = part[1023];
}

__global__ void scatter_kernel(const int* __restrict__ src, const int* __restrict__ dst,
                               const int* __restrict__ row_off, int* __restrict__ cur,
                               int* __restrict__ csr_src, int E) {
  int e = blockIdx.x * 256 + threadIdx.x;
  if (e < E) {
    int d = dst[e];
    int p = atomicAdd(&cur[d], 1);
    csr_src[row_off[d] + p] = src[e];
  }
}

// ======================= weight prep: transpose + bf16x2 split + chunk swizzle ==
// dst tile layout: [kt][col][chunk'][8 elems] bf16 ; chunk = chunk' ^ ((col>>1)&3)
// stacked K' = 3K: W' = [Whi ; Whi ; Wlo]  (pairs with A' = [Ahi | Alo | Ahi])
__global__ void wprep(const float* __restrict__ W, unsigned short* __restrict__ dst,
                      int K, int Nsz, int total) {
  int idx = blockIdx.x * 256 + threadIdx.x;
  if (idx >= total) return;
  int j = idx & 7;
  int c1 = (idx >> 3) & 3;
  int rest = idx >> 5;
  int col = rest % Nsz;
  int kt = rest / Nsz;
  int chunk = c1 ^ ((col >> 1) & 3);
  int kp = kt * 32 + chunk * 8 + j;
  int seg = kp / K;
  int k = kp - seg * K;
  float v = W[(size_t)k * Nsz + col];
  unsigned short h = f2bf(v);
  unsigned short o = (seg == 2) ? f2bf(v - bf2f(h)) : h;
  dst[(size_t)kt * Nsz * 32 + (size_t)col * 32 + c1 * 8 + j] = o;
}

// ======================= stacked-K bf16 MFMA GEMM ==============================
// C[M x N] = act(BN(A1'@W1' (+ A2'@W2') + bias)), A planes [M][640] bf16 (hi|lo)
// BM=96, BN=N=CW*80, 2 row-waves x CW col-waves, 3x5 16x16x32 frags per wave.
// MODE: 0 = f32 raw ; 1 = f32 bias+relu ; 2 = split bias+relu ; 3 = split bias+BN+relu
template<int CW, bool SRCF32, int SEGT, int NPASS, int MODE>
__global__ __launch_bounds__(128 * CW, 4) void mfma_gemm(
    const char* __restrict__ A1, const char* __restrict__ A2,
    const char* __restrict__ Wq,
    const float* __restrict__ bias, const float* __restrict__ gamma,
    const float* __restrict__ beta, void* __restrict__ outp, int M)
{
  static_assert(!SRCF32 || CW == 4, "");
  constexpr int TPB = 128 * CW;
  constexpr int N = CW * 80;
  constexpr int NT = NPASS * 3 * SEGT;
  constexpr int TILEB = N * 64;
  constexpr int AIT = (384 + TPB - 1) / TPB;
  __shared__ __align__(16) char ldsA[2 * 7680];
  __shared__ __align__(16) char ldsB[2 * TILEB];
  const int tid = threadIdx.x;
  const int lane = tid & 63;
  const int w = tid >> 6;
  const int rw = w & 1, cwv = w >> 1;
  const int bm = blockIdx.x * 96;
  const int kc = (lane >> 4) & 3;
  const int l15 = lane & 15;

  int aoff[3], boff[5];
  #pragma unroll
  for (int fr = 0; fr < 3; fr++) aoff[fr] = (rw * 48 + fr * 16 + l15) * 80 + kc * 16;
  #pragma unroll
  for (int cf = 0; cf < 5; cf++) {
    int col = cwv * 80 + cf * 16 + l15;
    boff[cf] = col * 64 + ((kc ^ ((col >> 1) & 3)) << 4);
  }

  f32x4 acc[3][5];
  #pragma unroll
  for (int i = 0; i < 3; i++)
    #pragma unroll
    for (int j = 0; j < 5; j++) { f32x4 z = {0.f, 0.f, 0.f, 0.f}; acc[i][j] = z; }

  f32x4 areg[AIT][2];
  auto issueA = [&](int t) -> bool {
    int pass = 0, tt = t;
    if constexpr (NPASS == 2) { pass = t / (3 * SEGT); tt = t - pass * (3 * SEGT); }
    int seg = tt / SEGT;
    int kk = tt - seg * SEGT;
    const char* __restrict__ base = pass ? A2 : A1;
    #pragma unroll
    for (int it = 0; it < AIT; it++) {
      int s = tid + it * TPB;
      if (s < 384) {
        int row = s >> 2, c = s & 3;
        int r = bm + row; if (r >= M) r = M - 1;
        if constexpr (SRCF32) {
          const char* p = base + (size_t)r * 512 + kk * 128 + c * 32;
          areg[it][0] = *(const f32x4*)p;
          areg[it][1] = *(const f32x4*)(p + 16);
        } else {
          const char* p = base + (size_t)r * 1280 + (seg == 1 ? 640 : 0) + kk * 64 + c * 16;
          areg[it][0] = *(const f32x4*)p;
        }
      }
    }
    return seg == 1;
  };
  auto writeA = [&](int buf, bool lo) {
    #pragma unroll
    for (int it = 0; it < AIT; it++) {
      int s = tid + it * TPB;
      if (s < 384) {
        int row = s >> 2, c = s & 3;
        char* d = &ldsA[buf * 7680 + row * 80 + c * 16];  // 80B pitch: 2-way banks = free
        if constexpr (SRCF32) {
          short8v v;
          #pragma unroll
          for (int j = 0; j < 8; j++) {
            float f = (j < 4) ? areg[it][0][j] : areg[it][1][j - 4];
            unsigned short h = f2bf(f);
            unsigned short o = lo ? f2bf(f - bf2f(h)) : h;
            v[j] = (short)o;
          }
          *(short8v*)d = v;
        } else {
          f32x4 t4 = areg[it][0];
          *(short8v*)d = *(short8v*)&t4;
        }
      }
    }
  };
  auto issueB = [&](int t, int buf) {
    const char* __restrict__ src = Wq + (size_t)t * TILEB;
    for (int s = tid; s < N * 4; s += TPB)
      gldlds16(src + (size_t)s * 16, &ldsB[buf * TILEB + s * 16]);
  };

  bool plo = issueA(0);
  issueB(0, 0);
  writeA(0, plo);
  __syncthreads();

  for (int t = 0; t < NT; ++t) {
    int curb = t & 1, nxt = curb ^ 1;
    bool lo = false;
    if (t + 1 < NT) { lo = issueA(t + 1); issueB(t + 1, nxt); }
    short8v af0 = *(const short8v*)&ldsA[curb * 7680 + aoff[0]];
    short8v af1 = *(const short8v*)&ldsA[curb * 7680 + aoff[1]];
    short8v af2 = *(const short8v*)&ldsA[curb * 7680 + aoff[2]];
    #pragma unroll
    for (int cf = 0; cf < 5; cf++) {
      short8v bv = *(const short8v*)&ldsB[curb * TILEB + boff[cf]];
      acc[0][cf] = __builtin_amdgcn_mfma_f32_16x16x32_bf16(af0, bv, acc[0][cf], 0, 0, 0);
      acc[1][cf] = __builtin_amdgcn_mfma_f32_16x16x32_bf16(af1, bv, acc[1][cf], 0, 0, 0);
      acc[2][cf] = __builtin_amdgcn_mfma_f32_16x16x32_bf16(af2, bv, acc[2][cf], 0, 0, 0);
    }
    if (t + 1 < NT) writeA(nxt, lo);
    __syncthreads();
  }

  const float bnrs = 0.99999500003749971f;  // 1/sqrt(1+1e-5)
  #pragma unroll
  for (int fr = 0; fr < 3; fr++) {
    int rbase = bm + rw * 48 + fr * 16 + (lane >> 4) * 4;
    #pragma unroll
    for (int cf = 0; cf < 5; cf++) {
      int col = cwv * 80 + cf * 16 + l15;
      float bi = 0.f, sc = 1.f, be = 0.f;
      if constexpr (MODE >= 1) bi = bias[col];
      if constexpr (MODE == 3) { sc = gamma[col] * bnrs; be = beta[col]; }
      #pragma unroll
      for (int rg = 0; rg < 4; rg++) {
        int r = rbase + rg;
        if (r < M) {
          float v = acc[fr][cf][rg];
          if constexpr (MODE >= 1) v += bi;
          if constexpr (MODE == 3) v = v * sc + be;
          if constexpr (MODE >= 1) v = v > 0.f ? v : 0.f;
          if constexpr (MODE >= 2) {
            unsigned short h = f2bf(v);
            unsigned short g = f2bf(v - bf2f(h));
            unsigned short* o = (unsigned short*)outp;
            o[(size_t)r * 640 + col] = h;
            o[(size_t)r * 640 + 320 + col] = g;
          } else {
            ((float*)outp)[(size_t)r * N + col] = v;
          }
        }
      }
    }
  }
}

// ======================= SAGE mean aggregation on split planes ==================
// half-wave (32 lanes) per node; rows are [320] dwords: hi dwords 0..159, lo 160..319
__global__ __launch_bounds__(256) void sage_agg_split(const unsigned* __restrict__ hp,
    const int* __restrict__ row_off, const int* __restrict__ csr_src,
    unsigned* __restrict__ outp, int n) {
  int node = blockIdx.x * 8 + (threadIdx.x >> 5);
  int lane = threadIdx.x & 31;
  if (node >= n) return;
  int beg = row_off[node], end = row_off[node + 1];
  float s0[5] = {0,0,0,0,0}, s1[5] = {0,0,0,0,0};
  float t0[5] = {0,0,0,0,0}, t1[5] = {0,0,0,0,0};
  for (int e = beg; e < end; e++) {
    const unsigned* row = hp + (size_t)csr_src[e] * 320;
    #pragma unroll
    for (int k = 0; k < 5; k++) {
      unsigned dh = row[lane + 32 * k];
      unsigned dl = row[160 + lane + 32 * k];
      s0[k] += bf2f((unsigned short)dh);
      s1[k] += bf2f((unsigned short)(dh >> 16));
      t0[k] += bf2f((unsigned short)dl);
      t1[k] += bf2f((unsigned short)(dl >> 16));
    }
  }
  int deg = end - beg;
  float inv = 1.0f / (float)(deg > 0 ? deg : 1);
  unsigned* orow = outp + (size_t)node * 320;
  #pragma unroll
  for (int k = 0; k < 5; k++) {
    float v0 = (s0[k] + t0[k]) * inv;
    float v1 = (s1[k] + t1[k]) * inv;
    unsigned short h0 = f2bf(v0), h1 = f2bf(v1);
    unsigned short g0 = f2bf(v0 - bf2f(h0)), g1 = f2bf(v1 - bf2f(h1));
    orow[lane + 32 * k] = (unsigned)h0 | ((unsigned)h1 << 16);
    orow[160 + lane + 32 * k] = (unsigned)g0 | ((unsigned)g1 << 16);
  }
}

// ======================= GAT: per-(node,head) attention dots ====================
__global__ void gat_prep(const float* __restrict__ xh,
    const float* __restrict__ asrc, const float* __restrict__ adst,
    float* __restrict__ al, float* __restrict__ ar, int n) {
  int idx = blockIdx.x * 256 + threadIdx.x;
  if (idx >= n * HEADS) return;
  int node = idx >> 2, hh = idx & 3;
  const f32x4* row = (const f32x4*)(xh + (size_t)node * HID + hh * HDIM);
  const f32x4* as = (const f32x4*)(asrc + hh * HDIM);
  const f32x4* ad = (const f32x4*)(adst + hh * HDIM);
  float sl = 0.f, sr = 0.f;
  #pragma unroll
  for (int d = 0; d < 20; d++) {
    f32x4 v = row[d], a = as[d], b = ad[d];
    #pragma unroll
    for (int j = 0; j < 4; j++) { sl += v[j] * a[j]; sr += v[j] * b[j]; }
  }
  al[idx] = sl;
  ar[idx] = sr;
}

// ======================= GAT aggregation: softmax + weighted sum + epilogue =====
// One wave per node. Self-loop score is the softmax shift (shift-invariance: exact).
// Lane->feature: head = lane>>4 (loop-invariant), feature = head*80 + (lane&15) + 16k.
// Scalar (SGPR) addressing via readfirstlane on the wave-uniform source index.
template<bool F32OUT>
__global__ __launch_bounds__(256) void gat_agg(const float* __restrict__ xh,
    const int* __restrict__ row_off, const int* __restrict__ csr_src,
    const float* __restrict__ al, const float* __restrict__ ar,
    const float* __restrict__ bias, const float* __restrict__ gamma,
    const float* __restrict__ beta, unsigned short* __restrict__ outS,
    float* __restrict__ outF, int n) {
  int node = (blockIdx.x << 2) + (threadIdx.x >> 6);
  int lane = threadIdx.x & 63;
  if (node >= n) return;
  int beg = row_off[node], end = row_off[node + 1];
  const int hh = lane >> 4;                 // head of this lane (loop-invariant)
  const int posb = hh * 80 + (lane & 15);   // features posb + 16k, k = 0..4

  float arv[4], sh[4];
  f32x4 a4i = *(const f32x4*)(al + (size_t)node * 4);
  #pragma unroll
  for (int h = 0; h < 4; h++) {
    arv[h] = ar[node * 4 + h];
    float v = a4i[h] + arv[h];
    sh[h] = fmaxf(v, NEG_SLOPE * v);        // self-loop score = stabilizing shift
  }
  float den[4] = {1.f, 1.f, 1.f, 1.f};      // self term: exp(0) = 1
  const float* selfrow = xh + (size_t)node * HID;
  float num[5];
  #pragma unroll
  for (int k = 0; k < 5; k++) num[k] = selfrow[posb + 16 * k];

  for (int e = beg; e < end; e++) {
    int s = __builtin_amdgcn_readfirstlane(csr_src[e]);
    f32x4 a4 = *(const f32x4*)(al + (size_t)s * 4);
    float ex[4];
    #pragma unroll
    for (int h = 0; h < 4; h++) {
      float v = a4[h] + arv[h];
      v = fmaxf(v, NEG_SLOPE * v);          // leaky_relu (slope>0: max form)
      float r = __expf(v - sh[h]);          // native v_mul+v_exp
      ex[h] = r;
      den[h] += r;
    }
    float exsel = hh < 2 ? (hh == 0 ? ex[0] : ex[1]) : (hh == 2 ? ex[2] : ex[3]);
    const float* __restrict__ row = xh + (size_t)s * HID;
    #pragma unroll
    for (int k = 0; k < 5; k++) num[k] += exsel * row[posb + 16 * k];
  }

  float dsel = hh < 2 ? (hh == 0 ? den[0] : den[1]) : (hh == 2 ? den[2] : den[3]);
  float dinv = 1.0f / dsel;                 // den >= 1 always
  const float bnrs = 0.99999500003749971f;  // 1/sqrt(1+1e-5)
  #pragma unroll
  for (int k = 0; k < 5; k++) {
    int p = posb + 16 * k;
    float v = num[k] * dinv + bias[p];
    v = v * (gamma[p] * bnrs) + beta[p];
    v = fmaxf(v, 0.f);
    unsigned short h2 = f2bf(v);
    outS[(size_t)node * 640 + p] = h2;
    outS[(size_t)node * 640 + 320 + p] = f2bf(v - bf2f(h2));
    if constexpr (F32OUT) outF[(size_t)node * 320 + p] = v;
  }
}

// ======================= classifier second layer ================================
__global__ void cls2_kernel(const float* __restrict__ tbuf, const float* __restrict__ w2,
                            const float* __restrict__ b2, float* __restrict__ out, int M) {
  int r = blockIdx.x * 256 + threadIdx.x;
  if (r >= M) return;
  const f32x4* row = (const f32x4*)(tbuf + (size_t)r * 160);
  float a0 = b2[0], a1 = b2[1];
  #pragma unroll
  for (int d4 = 0; d4 < 40; d4++) {
    f32x4 v = row[d4];
    #pragma unroll
    for (int j = 0; j < 4; j++) {
      int d = d4 * 4 + j;
      a0 += v[j] * w2[2 * d];
      a1 += v[j] * w2[2 * d + 1];
    }
  }
  out[2 * r] = a0;
  out[2 * r + 1] = a1;
}

// ======================= launch =======================
extern "C" void kernel_launch(void* const* d_in, const int* in_sizes, int n_in,
                              void* d_out, int out_size, void* d_ws, size_t ws_size,
                              hipStream_t stream) {
  const float* x    = (const float*)d_in[0];
  const int*   ei   = (const int*)d_in[1];
  const float* w_in = (const float*)d_in[2];
  const float* b_in = (const float*)d_in[3];
  const float* s0wl = (const float*)d_in[4];
  const float* s0bl = (const float*)d_in[5];
  const float* s0wr = (const float*)d_in[6];
  const float* g1w  = (const float*)d_in[7];
  const float* g1as = (const float*)d_in[8];
  const float* g1ad = (const float*)d_in[9];
  const float* g1b  = (const float*)d_in[10];
  const float* s2wl = (const float*)d_in[11];
  const float* s2bl = (const float*)d_in[12];
  const float* s2wr = (const float*)d_in[13];
  const float* g3w  = (const float*)d_in[14];
  const float* g3as = (const float*)d_in[15];
  const float* g3ad = (const float*)d_in[16];
  const float* g3b  = (const float*)d_in[17];
  const float* bng  = (const float*)d_in[18];
  const float* bnb  = (const float*)d_in[19];
  const float* cw1  = (const float*)d_in[20];
  const float* cb1  = (const float*)d_in[21];
  const float* cw2  = (const float*)d_in[22];
  const float* cb2  = (const float*)d_in[23];

  char* ws = (char*)d_ws;
  size_t off = 0;
  auto alloc = [&](size_t b) {
    void* p = (void*)(ws + off);
    off += (b + 255) & ~(size_t)255;
    return p;
  };
  const size_t SB = (size_t)MN * 1280;        // one split-plane matrix [M][640] bf16
  char* S0 = (char*)alloc(SB);
  char* S1 = (char*)alloc(SB);
  char* S2 = (char*)alloc(SB);
  char* WQ = (char*)alloc(4239360);
  float* al      = (float*)alloc((size_t)MN * HEADS * 4);
  float* ar      = (float*)alloc((size_t)MN * HEADS * 4);
  int*   row_off = (int*)alloc((size_t)(MN + 1) * 4);
  int*   hist    = (int*)alloc((size_t)MN * 4);
  int*   curw    = (int*)alloc((size_t)MN * 4);
  int*   csr     = (int*)alloc((size_t)EN * 4);

  float* outp = (float*)d_out;
  float* emb  = outp + (size_t)MN * 2;        // [M,320] fp32; doubles as xh1 scratch

  const int* srcp = ei;
  const int* dstp = ei + EN;

  // CSR
  hipMemsetAsync(hist, 0, MN * 4, stream);
  hipMemsetAsync(curw, 0, MN * 4, stream);
  hist_kernel<<<(EN + 255) / 256, 256, 0, stream>>>(dstp, hist, EN);
  scan_kernel<<<1, 1024, 0, stream>>>(hist, row_off, MN);
  scatter_kernel<<<(EN + 255) / 256, 256, 0, stream>>>(srcp, dstp, row_off, curw, csr, EN);

  // weight prep (stacked+transposed+split+swizzled): tile = Nsz*64 bytes
  char* wq_in = WQ + 0;        // 12 tiles of 20480
  char* wq_s0 = WQ + 245760;   // 60 tiles (wl 30 | wr 30)
  char* wq_g1 = WQ + 1474560;  // 30
  char* wq_s2 = WQ + 2088960;  // 60
  char* wq_g3 = WQ + 3317760;  // 30
  char* wq_cl = WQ + 3932160;  // 30 tiles of 10240
  int tot = 12 * 320 * 32;
  wprep<<<(tot + 255) / 256, 256, 0, stream>>>(w_in, (unsigned short*)wq_in, 128, 320, tot);
  tot = 30 * 320 * 32;
  wprep<<<(tot + 255) / 256, 256, 0, stream>>>(s0wl, (unsigned short*)wq_s0, 320, 320, tot);
  wprep<<<(tot + 255) / 256, 256, 0, stream>>>(s0wr, (unsigned short*)(wq_s0 + 614400), 320, 320, tot);
  wprep<<<(tot + 255) / 256, 256, 0, stream>>>(g1w,  (unsigned short*)wq_g1, 320, 320, tot);
  wprep<<<(tot + 255) / 256, 256, 0, stream>>>(s2wl, (unsigned short*)wq_s2, 320, 320, tot);
  wprep<<<(tot + 255) / 256, 256, 0, stream>>>(s2wr, (unsigned short*)(wq_s2 + 614400), 320, 320, tot);
  wprep<<<(tot + 255) / 256, 256, 0, stream>>>(g3w,  (unsigned short*)wq_g3, 320, 320, tot);
  tot = 30 * 160 * 32;
  wprep<<<(tot + 255) / 256, 256, 0, stream>>>(cw1, (unsigned short*)wq_cl, 320, 160, tot);

  const int gx = (MN + 95) / 96;   // 521
  const int ga = (MN + 3) / 4;
  const int gs = (MN + 7) / 8;

  // h0 = relu(x@w_in + b_in)  -> split S0
  mfma_gemm<4, true, 4, 1, 2><<<gx, 512, 0, stream>>>(
      (const char*)x, nullptr, wq_in, b_in, nullptr, nullptr, S0, MN);
  // SAGE0
  sage_agg_split<<<gs, 256, 0, stream>>>((const unsigned*)S0, row_off, csr, (unsigned*)S1, MN);
  mfma_gemm<4, false, 10, 2, 3><<<gx, 512, 0, stream>>>(
      S1, S0, wq_s0, s0bl, bng, bnb, S2, MN);
  // GAT1: xh1 -> emb region (fp32 scratch), result split -> S0
  mfma_gemm<4, false, 10, 1, 0><<<gx, 512, 0, stream>>>(
      S2, nullptr, wq_g1, nullptr, nullptr, nullptr, emb, MN);
  gat_prep<<<(MN * HEADS + 255) / 256, 256, 0, stream>>>(emb, g1as, g1ad, al, ar, MN);
  gat_agg<false><<<ga, 256, 0, stream>>>(
      emb, row_off, csr, al, ar, g1b, bng + 320, bnb + 320, (unsigned short*)S0, nullptr, MN);
  // SAGE2
  sage_agg_split<<<gs, 256, 0, stream>>>((const unsigned*)S0, row_off, csr, (unsigned*)S1, MN);
  mfma_gemm<4, false, 10, 2, 3><<<gx, 512, 0, stream>>>(
      S1, S0, wq_s2, s2bl, bng + 640, bnb + 640, S2, MN);
  // GAT3: xh3 -> S0 (fp32), emb fp32 -> d_out, split -> S1
  mfma_gemm<4, false, 10, 1, 0><<<gx, 512, 0, stream>>>(
      S2, nullptr, wq_g3, nullptr, nullptr, nullptr, S0, MN);
  gat_prep<<<(MN * HEADS + 255) / 256, 256, 0, stream>>>((const float*)S0, g3as, g3ad, al, ar, MN);
  gat_agg<true><<<ga, 256, 0, stream>>>(
      (const float*)S0, row_off, csr, al, ar, g3b, bng + 960, bnb + 960,
      (unsigned short*)S1, emb, MN);
  // classifier
  mfma_gemm<2, false, 10, 1, 1><<<gx, 256, 0, stream>>>(
      S1, nullptr, wq_cl, cb1, nullptr, nullptr, S2, MN);
  cls2_kernel<<<(MN + 255) / 256, 256, 0, stream>>>((const float*)S2, cw2, cb2, outp, MN);
}

// Round 11
// 1269.487 us; speedup vs baseline: 1.4824x; 1.1827x over previous
//
#include <hip/hip_runtime.h>
#include <cstdint>

#define MN 50000
#define EN 800000
#define HID 320
#define HEADS 4
#define HDIM 80
#define NEG_SLOPE 0.2f

typedef __attribute__((ext_vector_type(4))) float f32x4;
typedef __attribute__((ext_vector_type(8))) short short8v;

__device__ __forceinline__ unsigned short f2bf(float f){
  unsigned u = __float_as_uint(f);
  return (unsigned short)((u + 0x7fffu + ((u >> 16) & 1u)) >> 16);  // RNE
}
__device__ __forceinline__ float bf2f(unsigned short s){
  return __uint_as_float(((unsigned)s) << 16);
}
__device__ __forceinline__ void gldlds16(const void* g, void* l){
  __builtin_amdgcn_global_load_lds((const __attribute__((address_space(1))) void*)g,
                                   (__attribute__((address_space(3))) void*)l, 16, 0, 0);
}

// ======================= CSR build (counting sort by dst) =======================
__global__ void hist_kernel(const int* __restrict__ dst, int* __restrict__ hist, int E) {
  int e = blockIdx.x * 256 + threadIdx.x;
  if (e < E) atomicAdd(&hist[dst[e]], 1);
}

__global__ __launch_bounds__(1024) void scan_kernel(const int* __restrict__ hist,
                                                    int* __restrict__ row_off, int n) {
  __shared__ int part[1024];
  int t = threadIdx.x;
  int chunk = (n + 1023) >> 10;
  int beg = t * chunk, end = beg + chunk;
  if (end > n) end = n;
  if (beg > n) beg = n;
  int s = 0;
  for (int i = beg; i < end; i++) s += hist[i];
  part[t] = s;
  __syncthreads();
  for (int off = 1; off < 1024; off <<= 1) {
    int v = (t >= off) ? part[t - off] : 0;
    __syncthreads();
    if (t >= off) part[t] += v;
    __syncthreads();
  }
  int run = (t > 0) ? part[t - 1] : 0;
  for (int i = beg; i < end; i++) { row_off[i] = run; run += hist[i]; }
  if (t == 0) row_off[n] = part[1023];
}

__global__ void scatter_kernel(const int* __restrict__ src, const int* __restrict__ dst,
                               const int* __restrict__ row_off, int* __restrict__ cur,
                               int* __restrict__ csr_src, int E) {
  int e = blockIdx.x * 256 + threadIdx.x;
  if (e < E) {
    int d = dst[e];
    int p = atomicAdd(&cur[d], 1);
    csr_src[row_off[d] + p] = src[e];
  }
}

// ======================= weight prep: transpose + bf16x2 split + chunk swizzle ==
__global__ void wprep(const float* __restrict__ W, unsigned short* __restrict__ dst,
                      int K, int Nsz, int total) {
  int idx = blockIdx.x * 256 + threadIdx.x;
  if (idx >= total) return;
  int j = idx & 7;
  int c1 = (idx >> 3) & 3;
  int rest = idx >> 5;
  int col = rest % Nsz;
  int kt = rest / Nsz;
  int chunk = c1 ^ ((col >> 1) & 3);
  int kp = kt * 32 + chunk * 8 + j;
  int seg = kp / K;
  int k = kp - seg * K;
  float v = W[(size_t)k * Nsz + col];
  unsigned short h = f2bf(v);
  unsigned short o = (seg == 2) ? f2bf(v - bf2f(h)) : h;
  dst[(size_t)kt * Nsz * 32 + (size_t)col * 32 + c1 * 8 + j] = o;
}

// ======================= stacked-K bf16 MFMA GEMM ==============================
// MODE: 0 = f32 raw ; 1 = f32 bias+relu ; 2 = split bias+relu ;
//       3 = split bias+BN+relu ; 4 = split raw
template<int CW, bool SRCF32, int SEGT, int NPASS, int MODE>
__global__ __launch_bounds__(128 * CW, 4) void mfma_gemm(
    const char* __restrict__ A1, const char* __restrict__ A2,
    const char* __restrict__ Wq,
    const float* __restrict__ bias, const float* __restrict__ gamma,
    const float* __restrict__ beta, void* __restrict__ outp, int M)
{
  static_assert(!SRCF32 || CW == 4, "");
  constexpr int TPB = 128 * CW;
  constexpr int N = CW * 80;
  constexpr int NT = NPASS * 3 * SEGT;
  constexpr int TILEB = N * 64;
  constexpr int AIT = (384 + TPB - 1) / TPB;
  constexpr bool SPLITOUT = (MODE >= 2);
  constexpr bool HASBIAS = (MODE >= 1 && MODE <= 3);
  constexpr bool HASBN = (MODE == 3);
  constexpr bool HASRELU = (MODE >= 1 && MODE <= 3);
  __shared__ __align__(16) char ldsA[2 * 7680];
  __shared__ __align__(16) char ldsB[2 * TILEB];
  const int tid = threadIdx.x;
  const int lane = tid & 63;
  const int w = tid >> 6;
  const int rw = w & 1, cwv = w >> 1;
  const int bm = blockIdx.x * 96;
  const int kc = (lane >> 4) & 3;
  const int l15 = lane & 15;

  int aoff[3], boff[5];
  #pragma unroll
  for (int fr = 0; fr < 3; fr++) aoff[fr] = (rw * 48 + fr * 16 + l15) * 80 + kc * 16;
  #pragma unroll
  for (int cf = 0; cf < 5; cf++) {
    int col = cwv * 80 + cf * 16 + l15;
    boff[cf] = col * 64 + ((kc ^ ((col >> 1) & 3)) << 4);
  }

  f32x4 acc[3][5];
  #pragma unroll
  for (int i = 0; i < 3; i++)
    #pragma unroll
    for (int j = 0; j < 5; j++) { f32x4 z = {0.f, 0.f, 0.f, 0.f}; acc[i][j] = z; }

  f32x4 areg[AIT][2];
  auto issueA = [&](int t) -> bool {
    int pass = 0, tt = t;
    if constexpr (NPASS == 2) { pass = t / (3 * SEGT); tt = t - pass * (3 * SEGT); }
    int seg = tt / SEGT;
    int kk = tt - seg * SEGT;
    const char* __restrict__ base = pass ? A2 : A1;
    #pragma unroll
    for (int it = 0; it < AIT; it++) {
      int s = tid + it * TPB;
      if (s < 384) {
        int row = s >> 2, c = s & 3;
        int r = bm + row; if (r >= M) r = M - 1;
        if constexpr (SRCF32) {
          const char* p = base + (size_t)r * 512 + kk * 128 + c * 32;
          areg[it][0] = *(const f32x4*)p;
          areg[it][1] = *(const f32x4*)(p + 16);
        } else {
          const char* p = base + (size_t)r * 1280 + (seg == 1 ? 640 : 0) + kk * 64 + c * 16;
          areg[it][0] = *(const f32x4*)p;
        }
      }
    }
    return seg == 1;
  };
  auto writeA = [&](int buf, bool lo) {
    #pragma unroll
    for (int it = 0; it < AIT; it++) {
      int s = tid + it * TPB;
      if (s < 384) {
        int row = s >> 2, c = s & 3;
        char* d = &ldsA[buf * 7680 + row * 80 + c * 16];
        if constexpr (SRCF32) {
          short8v v;
          #pragma unroll
          for (int j = 0; j < 8; j++) {
            float f = (j < 4) ? areg[it][0][j] : areg[it][1][j - 4];
            unsigned short h = f2bf(f);
            unsigned short o = lo ? f2bf(f - bf2f(h)) : h;
            v[j] = (short)o;
          }
          *(short8v*)d = v;
        } else {
          f32x4 t4 = areg[it][0];
          *(short8v*)d = *(short8v*)&t4;
        }
      }
    }
  };
  auto issueB = [&](int t, int buf) {
    const char* __restrict__ src = Wq + (size_t)t * TILEB;
    for (int s = tid; s < N * 4; s += TPB)
      gldlds16(src + (size_t)s * 16, &ldsB[buf * TILEB + s * 16]);
  };

  bool plo = issueA(0);
  issueB(0, 0);
  writeA(0, plo);
  __syncthreads();

  for (int t = 0; t < NT; ++t) {
    int curb = t & 1, nxt = curb ^ 1;
    bool lo = false;
    if (t + 1 < NT) { lo = issueA(t + 1); issueB(t + 1, nxt); }
    short8v af0 = *(const short8v*)&ldsA[curb * 7680 + aoff[0]];
    short8v af1 = *(const short8v*)&ldsA[curb * 7680 + aoff[1]];
    short8v af2 = *(const short8v*)&ldsA[curb * 7680 + aoff[2]];
    #pragma unroll
    for (int cf = 0; cf < 5; cf++) {
      short8v bv = *(const short8v*)&ldsB[curb * TILEB + boff[cf]];
      acc[0][cf] = __builtin_amdgcn_mfma_f32_16x16x32_bf16(af0, bv, acc[0][cf], 0, 0, 0);
      acc[1][cf] = __builtin_amdgcn_mfma_f32_16x16x32_bf16(af1, bv, acc[1][cf], 0, 0, 0);
      acc[2][cf] = __builtin_amdgcn_mfma_f32_16x16x32_bf16(af2, bv, acc[2][cf], 0, 0, 0);
    }
    if (t + 1 < NT) writeA(nxt, lo);
    __syncthreads();
  }

  const float bnrs = 0.99999500003749971f;  // 1/sqrt(1+1e-5)
  #pragma unroll
  for (int fr = 0; fr < 3; fr++) {
    int rbase = bm + rw * 48 + fr * 16 + (lane >> 4) * 4;
    #pragma unroll
    for (int cf = 0; cf < 5; cf++) {
      int col = cwv * 80 + cf * 16 + l15;
      float bi = 0.f, sc = 1.f, be = 0.f;
      if constexpr (HASBIAS) bi = bias[col];
      if constexpr (HASBN) { sc = gamma[col] * bnrs; be = beta[col]; }
      #pragma unroll
      for (int rg = 0; rg < 4; rg++) {
        int r = rbase + rg;
        if (r < M) {
          float v = acc[fr][cf][rg];
          if constexpr (HASBIAS) v += bi;
          if constexpr (HASBN) v = v * sc + be;
          if constexpr (HASRELU) v = v > 0.f ? v : 0.f;
          if constexpr (SPLITOUT) {
            unsigned short h = f2bf(v);
            unsigned short g = f2bf(v - bf2f(h));
            unsigned short* o = (unsigned short*)outp;
            o[(size_t)r * 640 + col] = h;
            o[(size_t)r * 640 + 320 + col] = g;
          } else {
            ((float*)outp)[(size_t)r * N + col] = v;
          }
        }
      }
    }
  }
}

// ======================= SAGE mean aggregation: gather HI plane only ============
// half-wave (32 lanes) per node; rows are [320] dwords: hi dwords 0..159.
// Mean over ~deg independently-rounded bf16 values: rel err ~2^-9/sqrt(deg).
__global__ __launch_bounds__(256) void sage_agg_split(const unsigned* __restrict__ hp,
    const int* __restrict__ row_off, const int* __restrict__ csr_src,
    unsigned* __restrict__ outp, int n) {
  int node = blockIdx.x * 8 + (threadIdx.x >> 5);
  int lane = threadIdx.x & 31;
  if (node >= n) return;
  int beg = row_off[node], end = row_off[node + 1];
  float s0[5] = {0,0,0,0,0}, s1[5] = {0,0,0,0,0};
  for (int e = beg; e < end; e++) {
    const unsigned* row = hp + (size_t)csr_src[e] * 320;
    #pragma unroll
    for (int k = 0; k < 5; k++) {
      unsigned dh = row[lane + 32 * k];
      s0[k] += bf2f((unsigned short)dh);
      s1[k] += bf2f((unsigned short)(dh >> 16));
    }
  }
  int deg = end - beg;
  float inv = 1.0f / (float)(deg > 0 ? deg : 1);
  unsigned* orow = outp + (size_t)node * 320;
  #pragma unroll
  for (int k = 0; k < 5; k++) {
    float v0 = s0[k] * inv;
    float v1 = s1[k] * inv;
    unsigned short h0 = f2bf(v0), h1 = f2bf(v1);
    unsigned short g0 = f2bf(v0 - bf2f(h0)), g1 = f2bf(v1 - bf2f(h1));
    orow[lane + 32 * k] = (unsigned)h0 | ((unsigned)h1 << 16);
    orow[160 + lane + 32 * k] = (unsigned)g0 | ((unsigned)g1 << 16);
  }
}

// ======================= GAT: attention dots from split planes ==================
__global__ void gat_prep(const unsigned short* __restrict__ xs,
    const float* __restrict__ asrc, const float* __restrict__ adst,
    float* __restrict__ al, float* __restrict__ ar, int n) {
  int idx = blockIdx.x * 256 + threadIdx.x;
  if (idx >= n * HEADS) return;
  int node = idx >> 2, hh = idx & 3;
  const unsigned short* hi = xs + (size_t)node * 640 + hh * 80;
  const unsigned short* lo = hi + 320;
  const f32x4* as4 = (const f32x4*)(asrc + hh * HDIM);
  const f32x4* ad4 = (const f32x4*)(adst + hh * HDIM);
  float sl = 0.f, sr = 0.f;
  #pragma unroll
  for (int d8 = 0; d8 < 10; d8++) {
    short8v vh = *(const short8v*)(hi + d8 * 8);
    short8v vl = *(const short8v*)(lo + d8 * 8);
    f32x4 a0 = as4[2 * d8], a1 = as4[2 * d8 + 1];
    f32x4 b0 = ad4[2 * d8], b1 = ad4[2 * d8 + 1];
    #pragma unroll
    for (int j = 0; j < 4; j++) {
      float v = bf2f((unsigned short)vh[j]) + bf2f((unsigned short)vl[j]);
      sl += v * a0[j]; sr += v * b0[j];
    }
    #pragma unroll
    for (int j = 0; j < 4; j++) {
      float v = bf2f((unsigned short)vh[4 + j]) + bf2f((unsigned short)vl[4 + j]);
      sl += v * a1[j]; sr += v * b1[j];
    }
  }
  al[idx] = sl;
  ar[idx] = sr;
}

// ======================= GAT aggregation: HI-plane gather + softmax + epilogue ==
// Self term reconstructed from hi+lo (exact); neighbor features hi-only (averaged).
template<bool F32OUT>
__global__ __launch_bounds__(256) void gat_agg(const unsigned short* __restrict__ hp,
    const int* __restrict__ row_off, const int* __restrict__ csr_src,
    const float* __restrict__ al, const float* __restrict__ ar,
    const float* __restrict__ bias, const float* __restrict__ gamma,
    const float* __restrict__ beta, unsigned short* __restrict__ outS,
    float* __restrict__ outF, int n) {
  int node = (blockIdx.x << 2) + (threadIdx.x >> 6);
  int lane = threadIdx.x & 63;
  if (node >= n) return;
  int beg = row_off[node], end = row_off[node + 1];
  const int hh = lane >> 4;                 // head of this lane (loop-invariant)
  const int posb = hh * 80 + (lane & 15);   // features posb + 16k, k = 0..4

  float arv[4], sh[4];
  f32x4 a4i = *(const f32x4*)(al + (size_t)node * 4);
  #pragma unroll
  for (int h = 0; h < 4; h++) {
    arv[h] = ar[node * 4 + h];
    float v = a4i[h] + arv[h];
    sh[h] = fmaxf(v, NEG_SLOPE * v);        // self-loop score = stabilizing shift
  }
  float den[4] = {1.f, 1.f, 1.f, 1.f};      // self term: exp(0) = 1
  const unsigned short* selfrow = hp + (size_t)node * 640;
  float num[5];
  #pragma unroll
  for (int k = 0; k < 5; k++) {
    int p = posb + 16 * k;
    num[k] = bf2f(selfrow[p]) + bf2f(selfrow[320 + p]);  // exact self feature
  }

  for (int e = beg; e < end; e++) {
    int s = __builtin_amdgcn_readfirstlane(csr_src[e]);
    f32x4 a4 = *(const f32x4*)(al + (size_t)s * 4);
    float ex[4];
    #pragma unroll
    for (int h = 0; h < 4; h++) {
      float v = a4[h] + arv[h];
      v = fmaxf(v, NEG_SLOPE * v);          // leaky_relu
      float r = __expf(v - sh[h]);
      ex[h] = r;
      den[h] += r;
    }
    float exsel = hh < 2 ? (hh == 0 ? ex[0] : ex[1]) : (hh == 2 ? ex[2] : ex[3]);
    const unsigned short* __restrict__ row = hp + (size_t)s * 640;
    #pragma unroll
    for (int k = 0; k < 5; k++) num[k] += exsel * bf2f(row[posb + 16 * k]);
  }

  float dsel = hh < 2 ? (hh == 0 ? den[0] : den[1]) : (hh == 2 ? den[2] : den[3]);
  float dinv = 1.0f / dsel;                 // den >= 1 always
  const float bnrs = 0.99999500003749971f;  // 1/sqrt(1+1e-5)
  #pragma unroll
  for (int k = 0; k < 5; k++) {
    int p = posb + 16 * k;
    float v = num[k] * dinv + bias[p];
    v = v * (gamma[p] * bnrs) + beta[p];
    v = fmaxf(v, 0.f);
    unsigned short h2 = f2bf(v);
    outS[(size_t)node * 640 + p] = h2;
    outS[(size_t)node * 640 + 320 + p] = f2bf(v - bf2f(h2));
    if constexpr (F32OUT) outF[(size_t)node * 320 + p] = v;
  }
}

// ======================= classifier second layer ================================
__global__ void cls2_kernel(const float* __restrict__ tbuf, const float* __restrict__ w2,
                            const float* __restrict__ b2, float* __restrict__ out, int M) {
  int r = blockIdx.x * 256 + threadIdx.x;
  if (r >= M) return;
  const f32x4* row = (const f32x4*)(tbuf + (size_t)r * 160);
  float a0 = b2[0], a1 = b2[1];
  #pragma unroll
  for (int d4 = 0; d4 < 40; d4++) {
    f32x4 v = row[d4];
    #pragma unroll
    for (int j = 0; j < 4; j++) {
      int d = d4 * 4 + j;
      a0 += v[j] * w2[2 * d];
      a1 += v[j] * w2[2 * d + 1];
    }
  }
  out[2 * r] = a0;
  out[2 * r + 1] = a1;
}

// ======================= launch =======================
extern "C" void kernel_launch(void* const* d_in, const int* in_sizes, int n_in,
                              void* d_out, int out_size, void* d_ws, size_t ws_size,
                              hipStream_t stream) {
  const float* x    = (const float*)d_in[0];
  const int*   ei   = (const int*)d_in[1];
  const float* w_in = (const float*)d_in[2];
  const float* b_in = (const float*)d_in[3];
  const float* s0wl = (const float*)d_in[4];
  const float* s0bl = (const float*)d_in[5];
  const float* s0wr = (const float*)d_in[6];
  const float* g1w  = (const float*)d_in[7];
  const float* g1as = (const float*)d_in[8];
  const float* g1ad = (const float*)d_in[9];
  const float* g1b  = (const float*)d_in[10];
  const float* s2wl = (const float*)d_in[11];
  const float* s2bl = (const float*)d_in[12];
  const float* s2wr = (const float*)d_in[13];
  const float* g3w  = (const float*)d_in[14];
  const float* g3as = (const float*)d_in[15];
  const float* g3ad = (const float*)d_in[16];
  const float* g3b  = (const float*)d_in[17];
  const float* bng  = (const float*)d_in[18];
  const float* bnb  = (const float*)d_in[19];
  const float* cw1  = (const float*)d_in[20];
  const float* cb1  = (const float*)d_in[21];
  const float* cw2  = (const float*)d_in[22];
  const float* cb2  = (const float*)d_in[23];

  char* ws = (char*)d_ws;
  size_t off = 0;
  auto alloc = [&](size_t b) {
    void* p = (void*)(ws + off);
    off += (b + 255) & ~(size_t)255;
    return p;
  };
  const size_t SB = (size_t)MN * 1280;        // one split-plane matrix [M][640] bf16
  char* S0 = (char*)alloc(SB);
  char* S1 = (char*)alloc(SB);
  char* S2 = (char*)alloc(SB);
  char* WQ = (char*)alloc(4239360);
  float* al      = (float*)alloc((size_t)MN * HEADS * 4);
  float* ar      = (float*)alloc((size_t)MN * HEADS * 4);
  int*   row_off = (int*)alloc((size_t)(MN + 1) * 4);
  int*   hist    = (int*)alloc((size_t)MN * 4);
  int*   curw    = (int*)alloc((size_t)MN * 4);
  int*   csr     = (int*)alloc((size_t)EN * 4);

  float* outp = (float*)d_out;
  float* emb  = outp + (size_t)MN * 2;        // [M,320] fp32 slot; doubles as xh1 split scratch

  const int* srcp = ei;
  const int* dstp = ei + EN;

  // CSR
  hipMemsetAsync(hist, 0, MN * 4, stream);
  hipMemsetAsync(curw, 0, MN * 4, stream);
  hist_kernel<<<(EN + 255) / 256, 256, 0, stream>>>(dstp, hist, EN);
  scan_kernel<<<1, 1024, 0, stream>>>(hist, row_off, MN);
  scatter_kernel<<<(EN + 255) / 256, 256, 0, stream>>>(srcp, dstp, row_off, curw, csr, EN);

  // weight prep (stacked+transposed+split+swizzled): tile = Nsz*64 bytes
  char* wq_in = WQ + 0;        // 12 tiles of 20480
  char* wq_s0 = WQ + 245760;   // 60 tiles (wl 30 | wr 30)
  char* wq_g1 = WQ + 1474560;  // 30
  char* wq_s2 = WQ + 2088960;  // 60
  char* wq_g3 = WQ + 3317760;  // 30
  char* wq_cl = WQ + 3932160;  // 30 tiles of 10240
  int tot = 12 * 320 * 32;
  wprep<<<(tot + 255) / 256, 256, 0, stream>>>(w_in, (unsigned short*)wq_in, 128, 320, tot);
  tot = 30 * 320 * 32;
  wprep<<<(tot + 255) / 256, 256, 0, stream>>>(s0wl, (unsigned short*)wq_s0, 320, 320, tot);
  wprep<<<(tot + 255) / 256, 256, 0, stream>>>(s0wr, (unsigned short*)(wq_s0 + 614400), 320, 320, tot);
  wprep<<<(tot + 255) / 256, 256, 0, stream>>>(g1w,  (unsigned short*)wq_g1, 320, 320, tot);
  wprep<<<(tot + 255) / 256, 256, 0, stream>>>(s2wl, (unsigned short*)wq_s2, 320, 320, tot);
  wprep<<<(tot + 255) / 256, 256, 0, stream>>>(s2wr, (unsigned short*)(wq_s2 + 614400), 320, 320, tot);
  wprep<<<(tot + 255) / 256, 256, 0, stream>>>(g3w,  (unsigned short*)wq_g3, 320, 320, tot);
  tot = 30 * 160 * 32;
  wprep<<<(tot + 255) / 256, 256, 0, stream>>>(cw1, (unsigned short*)wq_cl, 320, 160, tot);

  const int gx = (MN + 95) / 96;   // 521
  const int ga = (MN + 3) / 4;
  const int gs = (MN + 7) / 8;

  // h0 = relu(x@w_in + b_in)  -> split S0
  mfma_gemm<4, true, 4, 1, 2><<<gx, 512, 0, stream>>>(
      (const char*)x, nullptr, wq_in, b_in, nullptr, nullptr, S0, MN);
  // SAGE0: hi-plane mean(S0) -> split S1 ; h1 = relu(BN0(...)) -> split S2
  sage_agg_split<<<gs, 256, 0, stream>>>((const unsigned*)S0, row_off, csr, (unsigned*)S1, MN);
  mfma_gemm<4, false, 10, 2, 3><<<gx, 512, 0, stream>>>(
      S1, S0, wq_s0, s0bl, bng, bnb, S2, MN);
  // GAT1: xh1 = S2@g1w -> SPLIT into emb region ; attn ; result split -> S0
  mfma_gemm<4, false, 10, 1, 4><<<gx, 512, 0, stream>>>(
      S2, nullptr, wq_g1, nullptr, nullptr, nullptr, emb, MN);
  gat_prep<<<(MN * HEADS + 255) / 256, 256, 0, stream>>>(
      (const unsigned short*)emb, g1as, g1ad, al, ar, MN);
  gat_agg<false><<<ga, 256, 0, stream>>>(
      (const unsigned short*)emb, row_off, csr, al, ar, g1b, bng + 320, bnb + 320,
      (unsigned short*)S0, nullptr, MN);
  // SAGE2: hi-plane mean(S0) -> split S1 ; h3 -> split S2
  sage_agg_split<<<gs, 256, 0, stream>>>((const unsigned*)S0, row_off, csr, (unsigned*)S1, MN);
  mfma_gemm<4, false, 10, 2, 3><<<gx, 512, 0, stream>>>(
      S1, S0, wq_s2, s2bl, bng + 640, bnb + 640, S2, MN);
  // GAT3: xh3 = S2@g3w -> SPLIT into S0 ; attn ; embeddings fp32 -> emb, split -> S1
  mfma_gemm<4, false, 10, 1, 4><<<gx, 512, 0, stream>>>(
      S2, nullptr, wq_g3, nullptr, nullptr, nullptr, S0, MN);
  gat_prep<<<(MN * HEADS + 255) / 256, 256, 0, stream>>>(
      (const unsigned short*)S0, g3as, g3ad, al, ar, MN);
  gat_agg<true><<<ga, 256, 0, stream>>>(
      (const unsigned short*)S0, row_off, csr, al, ar, g3b, bng + 960, bnb + 960,
      (unsigned short*)S1, emb, MN);
  // classifier
  mfma_gemm<2, false, 10, 1, 1><<<gx, 256, 0, stream>>>(
      S1, nullptr, wq_cl, cb1, nullptr, nullptr, S2, MN);
  cls2_kernel<<<(MN + 255) / 256, 256, 0, stream>>>((const float*)S2, cw2, cb2, outp, MN);
}